// Round 2
// baseline (81.707 us; speedup 1.0000x reference)
//
#include <hip/hip_runtime.h>

// SNN forward: 2-layer Leaky (subtract reset), BETA=0.95, THRESHOLD=1.0.
// x: [10, B, 4] f32, w1: [5,4] f32, w2: [3,5] f32.
// out: spk2_rec [10,B,3] f32 ++ mem2_rec [10,B,3] f32.
//
// Correctness strategy: replicate the numpy float32 reference BITWISE.
//  - dot products: sequential fmaf chain from 0 (sgemm microkernel order)
//  - leaky update: three separately-rounded f32 ops (mul, add, sub), no
//    contraction (pragma + __f*_rn intrinsics)
//  - spike: (mem > 1.0f), exactly equivalent to heaviside(mem - 1.0f)

#define NUM_STEPS  10
#define NUM_INPUT  4
#define NUM_HIDDEN 5
#define NUM_OUTPUT 3

__global__ __launch_bounds__(256) void snn_fwd_kernel(
    const float* __restrict__ x,   // [10, B, 4]
    const float* __restrict__ w1,  // [5, 4]
    const float* __restrict__ w2,  // [3, 5]
    float* __restrict__ out,       // spk2 [10,B,3] ++ mem2 [10,B,3]
    int batch)
{
#pragma clang fp contract(off)
    const int b = blockIdx.x * blockDim.x + threadIdx.x;
    if (b >= batch) return;

    // Weights: wave-uniform addresses -> scalar loads, broadcast to lanes.
    float W1[NUM_HIDDEN][NUM_INPUT];
#pragma unroll
    for (int h = 0; h < NUM_HIDDEN; ++h)
#pragma unroll
        for (int i = 0; i < NUM_INPUT; ++i)
            W1[h][i] = w1[h * NUM_INPUT + i];

    float W2[NUM_OUTPUT][NUM_HIDDEN];
#pragma unroll
    for (int o = 0; o < NUM_OUTPUT; ++o)
#pragma unroll
        for (int i = 0; i < NUM_HIDDEN; ++i)
            W2[o][i] = w2[o * NUM_HIDDEN + i];

    float mem1[NUM_HIDDEN] = {0.f, 0.f, 0.f, 0.f, 0.f};
    float mem2[NUM_OUTPUT] = {0.f, 0.f, 0.f};

    const long long B = (long long)batch;
    float* __restrict__ spk_out = out;                                    // [10,B,3]
    float* __restrict__ mem_out = out + (long long)NUM_STEPS * B * NUM_OUTPUT;

#pragma unroll
    for (int t = 0; t < NUM_STEPS; ++t) {
        // Coalesced 16B/lane vector load of this timestep's input row.
        const float4 xv =
            *reinterpret_cast<const float4*>(x + ((long long)t * B + b) * NUM_INPUT);
        const float xd[NUM_INPUT] = {xv.x, xv.y, xv.z, xv.w};

        // Layer 1: cur1 = x . w1[h], sgemm order: sequential fma from 0.
        float spk1[NUM_HIDDEN];
#pragma unroll
        for (int h = 0; h < NUM_HIDDEN; ++h) {
            float acc = 0.0f;
#pragma unroll
            for (int i = 0; i < NUM_INPUT; ++i)
                acc = fmaf(xd[i], W1[h][i], acc);
            const float reset = (mem1[h] > 1.0f) ? 1.0f : 0.0f;   // from PREVIOUS mem
            const float t1 = __fmul_rn(0.95f, mem1[h]);           // BETA*mem   (rounded)
            const float t2 = __fadd_rn(t1, acc);                  // + cur      (rounded)
            mem1[h] = __fsub_rn(t2, reset);                       // - reset    (rounded)
            spk1[h] = (mem1[h] > 1.0f) ? 1.0f : 0.0f;
        }

        // Layer 2: spk1 in {0,1} -> fma chain == separately-rounded adds.
        const long long base = ((long long)t * B + b) * NUM_OUTPUT;
#pragma unroll
        for (int o = 0; o < NUM_OUTPUT; ++o) {
            float acc = 0.0f;
#pragma unroll
            for (int i = 0; i < NUM_HIDDEN; ++i)
                acc = fmaf(spk1[i], W2[o][i], acc);
            const float reset = (mem2[o] > 1.0f) ? 1.0f : 0.0f;
            const float t1 = __fmul_rn(0.95f, mem2[o]);
            const float t2 = __fadd_rn(t1, acc);
            mem2[o] = __fsub_rn(t2, reset);
            spk_out[base + o] = (mem2[o] > 1.0f) ? 1.0f : 0.0f;
            mem_out[base + o] = mem2[o];
        }
    }
}

extern "C" void kernel_launch(void* const* d_in, const int* in_sizes, int n_in,
                              void* d_out, int out_size, void* d_ws, size_t ws_size,
                              hipStream_t stream)
{
    const float* x  = (const float*)d_in[0];
    const float* w1 = (const float*)d_in[1];
    const float* w2 = (const float*)d_in[2];
    float* out = (float*)d_out;

    const int batch = in_sizes[0] / (NUM_STEPS * NUM_INPUT);

    const int block = 256;
    const int grid = (batch + block - 1) / block;
    snn_fwd_kernel<<<grid, block, 0, stream>>>(x, w1, w2, out, batch);
}